// Round 3
// baseline (268.703 us; speedup 1.0000x reference)
//
#include <hip/hip_runtime.h>
#include <hip/hip_fp16.h>

#define IH   96
#define IW   320
#define NB   4
#define CIN  128
#define COUT 128
#define NKP  9
#define HW   (IH*IW)

typedef float    f32x4 __attribute__((ext_vector_type(4)));
typedef _Float16 f16x8 __attribute__((ext_vector_type(8)));

// ================= fused pre-pass =================
// blocks [0,3840): NCHW f32 -> NHWC f16   [3840,4416): weight prepack   [4416,8736): meta
__global__ __launch_bounds__(256) void k_pre(const float* __restrict__ feat,
                                             const float* __restrict__ off,
                                             const float* __restrict__ w,
                                             unsigned* __restrict__ nhwc,
                                             _Float16* __restrict__ wb,
                                             uint4* __restrict__ meta) {
    __shared__ float tile[32][129];
    int bid = blockIdx.x;
    int tid = threadIdx.x;

    if (bid < 3840) {                     // ---- transpose: b*IH*10 + y*10 + xc ----
        int xc = bid % 10;
        int by = bid / 10;
        int y = by % IH;
        int b = by / IH;
        int x0 = xc * 32;
        const float* src = feat + (size_t)b * CIN * HW + (size_t)y * IW + x0;
#pragma unroll
        for (int i = 0; i < 16; ++i) {
            int idx = tid + 256 * i;
            int c = idx >> 5, xl = idx & 31;
            tile[xl][c] = src[(size_t)c * HW + xl];
        }
        __syncthreads();
        unsigned* d = nhwc + ((size_t)(b * IH + y) * IW + x0) * 64;
#pragma unroll
        for (int i = 0; i < 8; ++i) {
            int idx = tid + 256 * i;
            int c2 = idx & 63, xl = idx >> 6;
            __half2 p;
            p.x = __float2half(tile[xl][2 * c2]);
            p.y = __float2half(tile[xl][2 * c2 + 1]);
            d[xl * 64 + c2] = *(unsigned*)&p;
        }
        return;
    }
    bid -= 3840;
    if (bid < 576) {                      // ---- weight prepack -> [kp][Cout][Cin] f16 ----
        int idx = bid * 256 + tid;
        int kp = idx >> 14;
        int cout = (idx >> 7) & 127;
        int c = idx & 127;
        wb[idx] = (_Float16)w[(cout * CIN + c) * NKP + kp];
        return;
    }
    bid -= 576;                           // ---- meta ----
    int idx = bid * 256 + tid;            // ((b*9+kp)*96+ho)*320+wo
    int wo = idx % IW;
    int t = idx / IW;
    int ho = t % IH;
    t /= IH;
    int kp = t % NKP;
    int b = t / NKP;

    float dy = off[((size_t)(b * 18 + 2 * kp) * IH + ho) * IW + wo];
    float dx = off[((size_t)(b * 18 + 2 * kp + 1) * IH + ho) * IW + wo];
    int ky = kp / 3, kx = kp - 3 * (kp / 3);
    float py = (float)(ho - 1 + ky) + dy;
    float px = (float)(wo - 1 + kx) + dx;
    float y0f = floorf(py), x0f = floorf(px);
    float wy1 = py - y0f, wx1 = px - x0f;
    float wy0 = 1.f - wy1, wx0 = 1.f - wx1;
    int y0 = (int)y0f, x0 = (int)x0f, y1 = y0 + 1, x1 = x0 + 1;
    wy0 = (y0 >= 0 && y0 < IH) ? wy0 : 0.f;
    wy1 = (y1 >= 0 && y1 < IH) ? wy1 : 0.f;
    wx0 = (x0 >= 0 && x0 < IW) ? wx0 : 0.f;
    wx1 = (x1 >= 0 && x1 < IW) ? wx1 : 0.f;
    int yc0 = min(max(y0, 0), IH - 1), yc1 = min(max(y1, 0), IH - 1);
    int xc0 = min(max(x0, 0), IW - 1), xc1 = min(max(x1, 0), IW - 1);
    unsigned r0 = (unsigned)((b * IH + yc0) * IW);
    unsigned r1 = (unsigned)((b * IH + yc1) * IW);
    auto pk = [](float wgt) {
        __half h = __float2half(wgt);
        __half2 p; p.x = h; p.y = h;
        return *(unsigned*)&p;
    };
    uint4 m0 = {pk(wy0 * wx0), pk(wy0 * wx1), pk(wy1 * wx0), pk(wy1 * wx1)};
    uint4 m1 = {(r0 + (unsigned)xc0) << 8, (r0 + (unsigned)xc1) << 8,
                (r1 + (unsigned)xc0) << 8, (r1 + (unsigned)xc1) << 8};
    meta[(size_t)idx * 2] = m0;
    meta[(size_t)idx * 2 + 1] = m1;
}

// ================= main fused kernel =================
// grid 960 (8 XCD x 120), 128 positions/block (2 subtiles of 64), 4 waves.
// LDS: double-buffered colbuf, XOR-swizzled. Per kp: 4x {stage4 | 8 MFMA | finish4}.
__global__ __launch_bounds__(256, 4) void k_main(const uint4* __restrict__ meta,
                                                 const char* __restrict__ fb,
                                                 const _Float16* __restrict__ wb,
                                                 float* __restrict__ out) {
    __shared__ unsigned colbuf[2 * 64 * 64];   // 32 KB
    char* cb_ = (char*)colbuf;

    const int tid  = threadIdx.x;
    const int lane = tid & 63;
    const int wv   = tid >> 6;
    const int posl = lane & 15;
    const int hi   = lane >> 4;
    const int x    = (posl & 7) << 2;                    // dword-index XOR
    const int vA   = (posl << 8) + (((4 * hi) ^ (x & 12)) << 2);
    const int xe   = (x & 16) << 2;
    const int xo   = xe ^ 64;
    const int l4   = lane << 2;
    const int wrb0 = l4 + (wv << 12);                    // ds_write per-lane base

    int bid = (blockIdx.x & 7) * 120 + (blockIdx.x >> 3);  // XCD chunked swizzle (960 = 8*120)
    const int n0 = bid * 128;
    const int b  = n0 / HW;                                // 240 blocks per batch, exact
    const int nrem0 = n0 - b * HW;

    // per-lane weight vaddr (elements): row = wv*32 + posl, kslice 8*hi
    const int wvoff = (wv * 32 + posl) * CIN + 8 * hi;

    for (int st = 0; st < 2; ++st) {
        const int nrem = nrem0 + st * 64;
        f32x4 acc[2][4];
#pragma unroll
        for (int mi = 0; mi < 2; ++mi)
#pragma unroll
            for (int nj = 0; nj < 4; ++nj)
                acc[mi][nj] = (f32x4){0.f, 0.f, 0.f, 0.f};

        // ---- prologue: sample kp=0 into buf0 ----
        {
            const int itBase = (b * NKP + 0) * HW + nrem + wv * 16;
#pragma unroll
            for (int i = 0; i < 16; ++i) {
                int it = __builtin_amdgcn_readfirstlane(itBase + i);
                uint4 mw = meta[(size_t)it * 2];
                uint4 ma = meta[(size_t)it * 2 + 1];
                unsigned u0 = *(const unsigned*)(fb + ma.x + l4);
                unsigned u1 = *(const unsigned*)(fb + ma.y + l4);
                unsigned u2 = *(const unsigned*)(fb + ma.z + l4);
                unsigned u3 = *(const unsigned*)(fb + ma.w + l4);
                __half2 s = __hmul2(*(const __half2*)&mw.x, *(const __half2*)&u0);
                s = __hfma2(*(const __half2*)&mw.y, *(const __half2*)&u1, s);
                s = __hfma2(*(const __half2*)&mw.z, *(const __half2*)&u2, s);
                s = __hfma2(*(const __half2*)&mw.w, *(const __half2*)&u3, s);
                *(unsigned*)(cb_ + (wrb0 ^ ((i & 7) << 4)) + (i << 8)) = *(unsigned*)&s;
            }
        }
        __syncthreads();

        for (int kp = 0; kp < NKP; ++kp) {
            const int cur = kp & 1;
            const int curB = cur << 14;
            const int nxtB = curB ^ (1 << 14);
            const int ave = vA + xe + curB;               // ds_read vaddr (even c0g)
            const int avo = vA + xo + curB;               // ds_read vaddr (odd  c0g)
            const int wrb = wrb0 + nxtB;                  // ds_write vaddr base
            const int itBase = (b * NKP + (kp + 1)) * HW + nrem + wv * 16;
            const bool more = (kp < NKP - 1);

            // weight fragments for this kp (issued first -> counted vmcnt)
            const _Float16* wk0 = wb + (size_t)kp * COUT * CIN + wvoff;
            const _Float16* wk1 = wk0 + 16 * CIN;
            f16x8 wl[2][4];
#pragma unroll
            for (int g = 0; g < 4; ++g) {
                wl[0][g] = *(const f16x8*)(wk0 + 32 * g);
                wl[1][g] = *(const f16x8*)(wk1 + 32 * g);
            }

#pragma unroll
            for (int q = 0; q < 4; ++q) {
                // ---- stage 4 items for kp+1 (issue loads, no use) ----
                uint4 mwv[4];
                unsigned ug[4][4];
                if (more) {
#pragma unroll
                    for (int i = 0; i < 4; ++i) {
                        int it = __builtin_amdgcn_readfirstlane(itBase + q * 4 + i);
                        mwv[i] = meta[(size_t)it * 2];
                        uint4 ma = meta[(size_t)it * 2 + 1];
                        ug[i][0] = *(const unsigned*)(fb + ma.x + l4);
                        ug[i][1] = *(const unsigned*)(fb + ma.y + l4);
                        ug[i][2] = *(const unsigned*)(fb + ma.z + l4);
                        ug[i][3] = *(const unsigned*)(fb + ma.w + l4);
                    }
                }
                // ---- MFMA quarter: c0g = q  (k = 32*q .. 32*q+31) ----
                {
                    const int sel = (q & 1) ? avo : ave;
                    const int himm = (q >> 1) << 7;
#pragma unroll
                    for (int nj = 0; nj < 4; ++nj) {
                        f16x8 bf = *(const f16x8*)(cb_ + sel + ((nj << 12) + himm));
                        acc[0][nj] = __builtin_amdgcn_mfma_f32_16x16x32_f16(wl[0][q], bf, acc[0][nj], 0, 0, 0);
                        acc[1][nj] = __builtin_amdgcn_mfma_f32_16x16x32_f16(wl[1][q], bf, acc[1][nj], 0, 0, 0);
                    }
                }
                // ---- finish 4 items: blend + ds_write to next buffer ----
                if (more) {
#pragma unroll
                    for (int i = 0; i < 4; ++i) {
                        __half2 s = __hmul2(*(const __half2*)&mwv[i].x, *(const __half2*)&ug[i][0]);
                        s = __hfma2(*(const __half2*)&mwv[i].y, *(const __half2*)&ug[i][1], s);
                        s = __hfma2(*(const __half2*)&mwv[i].z, *(const __half2*)&ug[i][2], s);
                        s = __hfma2(*(const __half2*)&mwv[i].w, *(const __half2*)&ug[i][3], s);
                        const int p = q * 4 + i;
                        *(unsigned*)(cb_ + (wrb ^ ((p & 7) << 4)) + (p << 8)) = *(unsigned*)&s;
                    }
                }
            }
            __syncthreads();
        }

        // ---- epilogue: C/D layout col=lane&15, row=hi*4+r ----
        float* obase = out + ((size_t)(b * COUT + wv * 32)) * HW + nrem;
#pragma unroll
        for (int mi = 0; mi < 2; ++mi) {
#pragma unroll
            for (int nj = 0; nj < 4; ++nj) {
                float* op = obase + (size_t)(mi * 16 + 4 * hi) * HW + nj * 16 + posl;
#pragma unroll
                for (int r = 0; r < 4; ++r)
                    op[(size_t)r * HW] = acc[mi][nj][r];
            }
        }
    }
}

extern "C" void kernel_launch(void* const* d_in, const int* in_sizes, int n_in,
                              void* d_out, int out_size, void* d_ws, size_t ws_size,
                              hipStream_t stream) {
    const float* features = (const float*)d_in[0];
    const float* offsets  = (const float*)d_in[1];
    const float* weight   = (const float*)d_in[2];
    float* out = (float*)d_out;

    unsigned*  nhwc = (unsigned*)d_ws;                                     // 31,457,280 B
    _Float16*  wbuf = (_Float16*)((char*)d_ws + (size_t)NB * HW * CIN * 2);
    uint4*     meta = (uint4*)((char*)d_ws + (size_t)NB * HW * CIN * 2 + 294912);

    hipLaunchKernelGGL(k_pre, dim3(8736), dim3(256), 0, stream,
                       features, offsets, weight, nhwc, wbuf, meta);
    hipLaunchKernelGGL(k_main, dim3(960), dim3(256), 0, stream,
                       meta, (const char*)nhwc, wbuf, out);
}